// Round 10
// baseline (166.649 us; speedup 1.0000x reference)
//
#include <hip/hip_runtime.h>
#include <math.h>

#define NN 512
#define MM 100
#define TPB 256
#define ROWS_OUT 4            // output rows per strip (= field tile rows)
#define ROWS_LDS 13           // staged input-row window
#define PXPT 8                // px per thread per plane

typedef float f32x4 __attribute__((ext_vector_type(4)));
typedef int   i32x2 __attribute__((ext_vector_type(2)));

// ws layout (floats):
//  St[51200] | B_u[51200] | B_v[51200] | w4[4*262144] | off2[2*262144] | strip_tab[256]

__global__ void sin_table_kernel(float* __restrict__ St) {
    int tid = blockIdx.x * blockDim.x + threadIdx.x;
    if (tid >= NN * MM) return;
    int x = tid / MM, j = tid % MM;
    double arg = M_PI * ((double)x / (double)(NN - 1)) * (double)(j + 1);
    St[tid] = (float)sin(arg);
}

__global__ void bcoef_kernel(const float* __restrict__ St,
                             const float* __restrict__ c_u,
                             const float* __restrict__ c_v,
                             float* __restrict__ B_u,
                             float* __restrict__ B_v) {
    int x = blockIdx.x;
    int j = threadIdx.x;
    if (j >= MM) return;
    float au = 0.f, av = 0.f;
    for (int i = 0; i < MM; ++i) {
        int i1 = i + 1, j1 = j + 1;
        int r2i = i1 * i1 + j1 * j1;
        float w = (r2i <= 10100) ? (1.0f / sqrtf((float)r2i)) : 0.0f;
        float sw = St[x * MM + i] * w;
        au += sw * c_u[i * MM + j];
        av += sw * c_v[i * MM + j];
    }
    B_u[j * NN + x] = au;
    B_v[j * NN + x] = av;
}

// Fused: displacement field + bilinear weights/offsets, computed ONCE per px
// (was recomputed per plane in remap -> 96x redundant VALU, R9 VALUBusy 43%).
// Block = one 4-row strip. Writes packed w4 (f32x4/px), rebased off2 (int2/px),
// and per-strip {r0, nr}.
__global__ __launch_bounds__(256)
void field_weights_kernel(const float* __restrict__ St,
                          const float* __restrict__ B_u,
                          const float* __restrict__ B_v,
                          float scale,
                          f32x4* __restrict__ w4,
                          i32x2* __restrict__ off2,
                          int* __restrict__ strip_tab) {
    __shared__ float sS[ROWS_OUT * MM];
    __shared__ int s_mn[4], s_mx[4];
    int t = threadIdx.x;
    int strip = blockIdx.x;
    int y0 = strip * ROWS_OUT;

    for (int i = t; i < ROWS_OUT * MM; i += 256) {
        int r = i / MM, j = i % MM;
        sS[i] = St[(y0 + r) * MM + j];
    }
    __syncthreads();

    float au[ROWS_OUT][2] = {}, av[ROWS_OUT][2] = {};
    for (int j = 0; j < MM; ++j) {
        float bu0 = B_u[j * NN + t], bu1 = B_u[j * NN + t + 256];
        float bv0 = B_v[j * NN + t], bv1 = B_v[j * NN + t + 256];
        #pragma unroll
        for (int r = 0; r < ROWS_OUT; ++r) {
            float s = sS[r * MM + j];        // wave-uniform -> broadcast
            au[r][0] += bu0 * s; au[r][1] += bu1 * s;
            av[r][0] += bv0 * s; av[r][1] += bv1 * s;
        }
    }

    float w00[PXPT], w01[PXPT], w10[PXPT], w11[PXPT];
    int offA[PXPT], offB[PXPT];
    int myf = NN, Myc = -1;
    #pragma unroll
    for (int i = 0; i < PXPT; ++i) {
        int c = i & 1, r = i >> 1;
        int xi = (c << 8) + t;
        int yi = y0 + r;
        float xn = fminf(fmaxf((float)xi - scale * au[r][c], 0.0f), (float)(NN - 1));
        float yn = fminf(fmaxf((float)yi - scale * av[r][c], 0.0f), (float)(NN - 1));
        int xf = (int)floorf(xn), yf = (int)floorf(yn);
        int yc = (int)ceilf(yn);
        float xv = xn - (float)xf, yv = yn - (float)yf;
        w00[i] = (1.f - yv) * (1.f - xv);
        w01[i] = (1.f - yv) * xv;
        w10[i] = yv * (1.f - xv);
        w11[i] = yv * xv;
        offA[i] = (yf << 9) + xf;
        offB[i] = (yc << 9) + xf;
        myf = min(myf, yf);
        Myc = max(Myc, yc);
    }

    for (int d = 32; d; d >>= 1) {
        myf = min(myf, __shfl_xor(myf, d));
        Myc = max(Myc, __shfl_xor(Myc, d));
    }
    int wid = t >> 6;
    if ((t & 63) == 0) { s_mn[wid] = myf; s_mx[wid] = Myc; }
    __syncthreads();
    int r0 = min(min(s_mn[0], s_mn[1]), min(s_mn[2], s_mn[3]));
    int nr = max(max(s_mx[0], s_mx[1]), max(s_mx[2], s_mx[3])) - r0 + 1;
    if (t == 0) { strip_tab[2 * strip] = r0; strip_tab[2 * strip + 1] = nr; }

    int rb = r0 << 9;
    #pragma unroll
    for (int i = 0; i < PXPT; ++i) {
        int pix = ((y0 + (i >> 1)) << 9) + ((i & 1) << 8) + t;
        f32x4 w; w[0] = w00[i]; w[1] = w01[i]; w[2] = w10[i]; w[3] = w11[i];
        i32x2 o; o[0] = offA[i] - rb; o[1] = offB[i] - rb;
        w4[pix] = w;
        off2[pix] = o;
    }
}

// One plane per block: stage -> ONE drain barrier -> 4 LDS reads + 4 FMA/px.
// All addressing/weights preloaded (plane-invariant).
__global__ __launch_bounds__(TPB, 6)
void remap_kernel(const float* __restrict__ img,
                  const f32x4* __restrict__ w4,
                  const i32x2* __restrict__ off2,
                  const int* __restrict__ strip_tab,
                  float* __restrict__ out,
                  int planes) {
    __shared__ __align__(16) float rows[ROWS_LDS * NN + 1];

    // XCD-bijective swizzle (gridDim.x % 8 == 0), plane-major: adjacent
    // strips (sharing halo rows + weight slices) adjacent on one XCD.
    int nb = gridDim.x;
    int bid = blockIdx.x;
    int sid = (bid & 7) * (nb >> 3) + (bid >> 3);
    int plane = sid >> 7;        // 128 strips per plane
    int strip = sid & 127;

    int t = threadIdx.x;
    int r0 = strip_tab[2 * strip];
    int nr = strip_tab[2 * strip + 1];

    const float* __restrict__ ip = img + (size_t)plane * (NN * NN);
    float* __restrict__ op = out + (size_t)plane * (NN * NN);
    int base = ((strip * ROWS_OUT) << 9) + t;

    if (nr <= ROWS_LDS) {
        // pad slot: read only with weight exactly 0 (xf==511 -> w01=w11=0);
        // DMA writes [0, nr*NN) floats, never touches it
        if (t == 0) rows[nr * NN] = 0.f;

        int nbytes = nr << 11;
        int wave = t >> 6;
        int lane_goff = t * 16;
        const char* ipc = (const char*)(ip + (r0 << 9));
        for (int ob = 0; ob < nbytes; ob += TPB * 16) {
            if (ob + wave * 1024 < nbytes) {
                __builtin_amdgcn_global_load_lds(
                    (const __attribute__((address_space(1))) void*)(ipc + ob + lane_goff),
                    (__attribute__((address_space(3))) void*)((char*)rows + ob + wave * 1024),
                    16, 0, 0);
            }
        }
        __syncthreads();

        #pragma unroll
        for (int i = 0; i < PXPT; ++i) {
            int pix = base + ((i >> 1) << 9) + ((i & 1) << 8);
            f32x4 w = w4[pix];
            i32x2 o2 = off2[pix];
            float o = w[0] * rows[o2[0]] + w[1] * rows[o2[0] + 1]
                    + w[2] * rows[o2[1]] + w[3] * rows[o2[1] + 1];
            __builtin_nontemporal_store(o, op + pix);
        }
    } else {
        // fallback: direct global gathers (correct for any dy range)
        int rb = r0 << 9;
        #pragma unroll
        for (int i = 0; i < PXPT; ++i) {
            int pix = base + ((i >> 1) << 9) + ((i & 1) << 8);
            f32x4 w = w4[pix];
            i32x2 o2 = off2[pix];
            int a = o2[0] + rb, b = o2[1] + rb;
            int e1 = ((a & 511) == 511) ? 0 : 1;
            float o = w[0] * ip[a] + w[1] * ip[a + e1]
                    + w[2] * ip[b] + w[3] * ip[b + e1];
            __builtin_nontemporal_store(o, op + pix);
        }
    }
}

extern "C" void kernel_launch(void* const* d_in, const int* in_sizes, int n_in,
                              void* d_out, int out_size, void* d_ws, size_t ws_size,
                              hipStream_t stream) {
    const float* img = (const float*)d_in[0];
    const float* c_u = (const float*)d_in[1];
    const float* c_v = (const float*)d_in[2];
    float* out = (float*)d_out;

    int planes = in_sizes[0] / (NN * NN);   // 96

    float* ws   = (float*)d_ws;
    float* St   = ws;                        // 51200
    float* B_u  = St + NN * MM;              // 51200
    float* B_v  = B_u + MM * NN;             // 51200
    f32x4* w4   = (f32x4*)(ws + 153600);     // 262144 * f32x4 (4 MB)
    i32x2* off2 = (i32x2*)(ws + 153600 + 4 * NN * NN);   // 2 MB
    int* strip_tab = (int*)(ws + 153600 + 6 * NN * NN);  // 256 ints

    double log_cut = log((double)MM + 1e-6);
    double T1 = 1.0 / (M_PI * (double)NN * (double)NN * log_cut);
    double T2 = 4.0 / (M_PI * M_PI * M_PI * (double)MM * (double)MM * log_cut);
    if (T2 < T1) T2 = T1;
    double T = 0.5 * (T1 + T2);
    float scale = (float)(sqrt(T) * (double)NN);

    sin_table_kernel<<<(NN * MM + 255) / 256, 256, 0, stream>>>(St);
    bcoef_kernel<<<NN, 128, 0, stream>>>(St, c_u, c_v, B_u, B_v);
    field_weights_kernel<<<NN / ROWS_OUT, 256, 0, stream>>>(St, B_u, B_v, scale,
                                                            w4, off2, strip_tab);

    int strips = NN / ROWS_OUT;                  // 128
    remap_kernel<<<strips * planes, TPB, 0, stream>>>(img, w4, off2, strip_tab,
                                                      out, planes);
}

// Round 11
// 80.947 us; speedup vs baseline: 2.0587x; 2.0587x over previous
//
#include <hip/hip_runtime.h>
#include <math.h>

#define NN 512
#define MM 100
#define TPB 256
#define ROWS_OUT 4            // output rows per strip
#define ROWS_LDS 13           // staged input-row window
#define PXPT 8                // px per thread per plane

typedef float f32x4 __attribute__((ext_vector_type(4)));
typedef unsigned int u32;
typedef u32 u32x2 __attribute__((ext_vector_type(2)));

// ws layout (floats): St[51200] | B_u[51200] | B_v[51200] | pk[2*262144 u32] | strip_tab[256]

__global__ void sin_table_kernel(float* __restrict__ St) {
    int tid = blockIdx.x * blockDim.x + threadIdx.x;
    if (tid >= NN * MM) return;
    int x = tid / MM, j = tid % MM;
    double arg = M_PI * ((double)x / (double)(NN - 1)) * (double)(j + 1);
    St[tid] = (float)sin(arg);
}

__global__ void bcoef_kernel(const float* __restrict__ St,
                             const float* __restrict__ c_u,
                             const float* __restrict__ c_v,
                             float* __restrict__ B_u,
                             float* __restrict__ B_v) {
    int x = blockIdx.x;
    int j = threadIdx.x;
    if (j >= MM) return;
    float au = 0.f, av = 0.f;
    for (int i = 0; i < MM; ++i) {
        int i1 = i + 1, j1 = j + 1;
        int r2i = i1 * i1 + j1 * j1;
        float w = (r2i <= 10100) ? (1.0f / sqrtf((float)r2i)) : 0.0f;
        float sw = St[x * MM + i] * w;
        au += sw * c_u[i * MM + j];
        av += sw * c_v[i * MM + j];
    }
    B_u[j * NN + x] = au;
    B_v[j * NN + x] = av;
}

// Fused field + COMPRESSED per-px remap table: 8 B/px (same L2 footprint as
// R9's dx/dy re-reads -> FETCH stays ~62 MB; R10's 24 B/px blew L2 -> 350 MB).
// pk[pix] = { offA | offB<<16 (window-rebased), xv_u16 | yv_u16<<16 }.
__global__ __launch_bounds__(256)
void field_weights_kernel(const float* __restrict__ St,
                          const float* __restrict__ B_u,
                          const float* __restrict__ B_v,
                          float scale,
                          u32x2* __restrict__ pk,
                          int* __restrict__ strip_tab) {
    __shared__ float sS[ROWS_OUT * MM];
    __shared__ int s_mn[4], s_mx[4];
    int t = threadIdx.x;
    int strip = blockIdx.x;
    int y0 = strip * ROWS_OUT;

    for (int i = t; i < ROWS_OUT * MM; i += 256) {
        int r = i / MM, j = i % MM;
        sS[i] = St[(y0 + r) * MM + j];
    }
    __syncthreads();

    float au[ROWS_OUT][2] = {}, av[ROWS_OUT][2] = {};
    for (int j = 0; j < MM; ++j) {
        float bu0 = B_u[j * NN + t], bu1 = B_u[j * NN + t + 256];
        float bv0 = B_v[j * NN + t], bv1 = B_v[j * NN + t + 256];
        #pragma unroll
        for (int r = 0; r < ROWS_OUT; ++r) {
            float s = sS[r * MM + j];        // wave-uniform -> broadcast
            au[r][0] += bu0 * s; au[r][1] += bu1 * s;
            av[r][0] += bv0 * s; av[r][1] += bv1 * s;
        }
    }

    float xvq[PXPT], yvq[PXPT];
    int offA[PXPT], offB[PXPT];
    int myf = NN, Myc = -1;
    #pragma unroll
    for (int i = 0; i < PXPT; ++i) {
        int c = i & 1, r = i >> 1;
        int xi = (c << 8) + t;
        int yi = y0 + r;
        float xn = fminf(fmaxf((float)xi - scale * au[r][c], 0.0f), (float)(NN - 1));
        float yn = fminf(fmaxf((float)yi - scale * av[r][c], 0.0f), (float)(NN - 1));
        int xf = (int)floorf(xn), yf = (int)floorf(yn);
        int yc = (int)ceilf(yn);
        xvq[i] = xn - (float)xf;
        yvq[i] = yn - (float)yf;
        offA[i] = (yf << 9) + xf;
        offB[i] = (yc << 9) + xf;
        myf = min(myf, yf);
        Myc = max(Myc, yc);
    }

    for (int d = 32; d; d >>= 1) {
        myf = min(myf, __shfl_xor(myf, d));
        Myc = max(Myc, __shfl_xor(Myc, d));
    }
    int wid = t >> 6;
    if ((t & 63) == 0) { s_mn[wid] = myf; s_mx[wid] = Myc; }
    __syncthreads();
    int r0 = min(min(s_mn[0], s_mn[1]), min(s_mn[2], s_mn[3]));
    int nr = max(max(s_mx[0], s_mx[1]), max(s_mx[2], s_mx[3])) - r0 + 1;
    if (t == 0) { strip_tab[2 * strip] = r0; strip_tab[2 * strip + 1] = nr; }

    int rb = r0 << 9;
    #pragma unroll
    for (int i = 0; i < PXPT; ++i) {
        int pix = ((y0 + (i >> 1)) << 9) + ((i & 1) << 8) + t;
        u32 oa = (u32)(offA[i] - rb);          // fits 16 bits for nr <= 127
        u32 ob = (u32)(offB[i] - rb);
        u32 xq = (u32)__float2int_rn(xvq[i] * 65535.0f);
        u32 yq = (u32)__float2int_rn(yvq[i] * 65535.0f);
        u32x2 v; v[0] = oa | (ob << 16); v[1] = xq | (yq << 16);
        pk[pix] = v;
    }
}

// One plane per block: DMA-stage window -> ONE drain barrier -> per px:
// 1 dwordx2 table load + cheap unpack (~14 VALU) + 4 LDS reads + nt store.
__global__ __launch_bounds__(TPB, 6)
void remap_kernel(const float* __restrict__ img,
                  const u32x2* __restrict__ pk,
                  const int* __restrict__ strip_tab,
                  float* __restrict__ out,
                  int planes) {
    __shared__ __align__(16) float rows[ROWS_LDS * NN + 1];

    // XCD-bijective swizzle (gridDim.x % 8 == 0), plane-major: adjacent
    // strips (sharing halo rows + table slices) adjacent on one XCD.
    int nb = gridDim.x;
    int bid = blockIdx.x;
    int sid = (bid & 7) * (nb >> 3) + (bid >> 3);
    int plane = sid >> 7;        // 128 strips per plane
    int strip = sid & 127;

    int t = threadIdx.x;
    int r0 = strip_tab[2 * strip];
    int nr = strip_tab[2 * strip + 1];

    const float* __restrict__ ip = img + (size_t)plane * (NN * NN);
    float* __restrict__ op = out + (size_t)plane * (NN * NN);
    int base = ((strip * ROWS_OUT) << 9) + t;

    const float qs = 1.0f / 65535.0f;

    if (nr <= ROWS_LDS) {
        // pad slot: read only with weight exactly 0 (xf==511 -> xv=0)
        if (t == 0) rows[nr * NN] = 0.f;

        int nbytes = nr << 11;
        int wave = t >> 6;
        int lane_goff = t * 16;
        const char* ipc = (const char*)(ip + (r0 << 9));
        for (int ob = 0; ob < nbytes; ob += TPB * 16) {
            if (ob + wave * 1024 < nbytes) {
                __builtin_amdgcn_global_load_lds(
                    (const __attribute__((address_space(1))) void*)(ipc + ob + lane_goff),
                    (__attribute__((address_space(3))) void*)((char*)rows + ob + wave * 1024),
                    16, 0, 0);
            }
        }
        __syncthreads();

        #pragma unroll
        for (int i = 0; i < PXPT; ++i) {
            int pix = base + ((i >> 1) << 9) + ((i & 1) << 8);
            u32x2 p = pk[pix];
            int oA = (int)(p[0] & 0xFFFFu);
            int oB = (int)(p[0] >> 16);
            float xv = (float)(p[1] & 0xFFFFu) * qs;
            float yv = (float)(p[1] >> 16) * qs;
            float omx = 1.f - xv, omy = 1.f - yv;
            float top = omx * rows[oA] + xv * rows[oA + 1];
            float bot = omx * rows[oB] + xv * rows[oB + 1];
            float o = omy * top + yv * bot;
            __builtin_nontemporal_store(o, op + pix);
        }
    } else {
        // fallback: direct global gathers (valid for nr <= 127; never seen >13)
        int rb = r0 << 9;
        #pragma unroll
        for (int i = 0; i < PXPT; ++i) {
            int pix = base + ((i >> 1) << 9) + ((i & 1) << 8);
            u32x2 p = pk[pix];
            int a = (int)(p[0] & 0xFFFFu) + rb;
            int b = (int)(p[0] >> 16) + rb;
            float xv = (float)(p[1] & 0xFFFFu) * qs;
            float yv = (float)(p[1] >> 16) * qs;
            float omx = 1.f - xv, omy = 1.f - yv;
            int e1 = ((a & 511) == 511) ? 0 : 1;
            float top = omx * ip[a] + xv * ip[a + e1];
            float bot = omx * ip[b] + xv * ip[b + e1];
            float o = omy * top + yv * bot;
            __builtin_nontemporal_store(o, op + pix);
        }
    }
}

extern "C" void kernel_launch(void* const* d_in, const int* in_sizes, int n_in,
                              void* d_out, int out_size, void* d_ws, size_t ws_size,
                              hipStream_t stream) {
    const float* img = (const float*)d_in[0];
    const float* c_u = (const float*)d_in[1];
    const float* c_v = (const float*)d_in[2];
    float* out = (float*)d_out;

    int planes = in_sizes[0] / (NN * NN);   // 96

    float* ws   = (float*)d_ws;
    float* St   = ws;                        // 51200
    float* B_u  = St + NN * MM;              // 51200
    float* B_v  = B_u + MM * NN;             // 51200
    u32x2* pk   = (u32x2*)(ws + 153600);     // 262144 * 8 B = 2 MB
    int* strip_tab = (int*)(ws + 153600 + 2 * NN * NN);  // 256 ints

    double log_cut = log((double)MM + 1e-6);
    double T1 = 1.0 / (M_PI * (double)NN * (double)NN * log_cut);
    double T2 = 4.0 / (M_PI * M_PI * M_PI * (double)MM * (double)MM * log_cut);
    if (T2 < T1) T2 = T1;
    double T = 0.5 * (T1 + T2);
    float scale = (float)(sqrt(T) * (double)NN);

    sin_table_kernel<<<(NN * MM + 255) / 256, 256, 0, stream>>>(St);
    bcoef_kernel<<<NN, 128, 0, stream>>>(St, c_u, c_v, B_u, B_v);
    field_weights_kernel<<<NN / ROWS_OUT, 256, 0, stream>>>(St, B_u, B_v, scale,
                                                            pk, strip_tab);

    int strips = NN / ROWS_OUT;                  // 128
    remap_kernel<<<strips * planes, TPB, 0, stream>>>(img, pk, strip_tab,
                                                      out, planes);
}

// Round 12
// 75.865 us; speedup vs baseline: 2.1966x; 1.0670x over previous
//
#include <hip/hip_runtime.h>
#include <math.h>

#define NN 512
#define MM 100
#define TPB 256
#define ROWS_OUT 4            // output rows per strip
#define ROWS_LDS 13           // staged input-row window
#define PXPT 8                // px per thread per plane (4 rows x 2 adjacent cols)

typedef float f32x2 __attribute__((ext_vector_type(2)));
typedef unsigned int u32;
typedef u32 u32x2 __attribute__((ext_vector_type(2)));
typedef u32 u32x4 __attribute__((ext_vector_type(4)));

// ws layout (floats): B_u[51200] | B_v[51200] | pk[2*262144 u32] | strip_tab[256]

__global__ void bcoef_kernel(const float* __restrict__ c_u,
                             const float* __restrict__ c_v,
                             float* __restrict__ B_u,
                             float* __restrict__ B_v) {
    __shared__ float sSt[MM];
    int x = blockIdx.x;
    int j = threadIdx.x;
    if (j < MM) {
        double arg = M_PI * ((double)x / (double)(NN - 1)) * (double)(j + 1);
        sSt[j] = (float)sin(arg);
    }
    __syncthreads();
    if (j >= MM) return;
    float au = 0.f, av = 0.f;
    for (int i = 0; i < MM; ++i) {
        int i1 = i + 1, j1 = j + 1;
        int r2i = i1 * i1 + j1 * j1;
        float w = (r2i <= 10100) ? (1.0f / sqrtf((float)r2i)) : 0.0f;
        float sw = sSt[i] * w;
        au += sw * c_u[i * MM + j];
        av += sw * c_v[i * MM + j];
    }
    B_u[j * NN + x] = au;
    B_v[j * NN + x] = av;
}

// Fused field + compressed per-px remap table: 8 B/px (L2-resident per plane;
// R10's 24 B/px blew L2). pk[pix] = { offA | offB<<16, xv_u16 | yv_u16<<16 }.
__global__ __launch_bounds__(256)
void field_weights_kernel(const float* __restrict__ B_u,
                          const float* __restrict__ B_v,
                          float scale,
                          u32x2* __restrict__ pk,
                          int* __restrict__ strip_tab) {
    __shared__ float sS[ROWS_OUT * MM];
    __shared__ int s_mn[4], s_mx[4];
    int t = threadIdx.x;
    int strip = blockIdx.x;
    int y0 = strip * ROWS_OUT;

    for (int i = t; i < ROWS_OUT * MM; i += 256) {
        int r = i / MM, j = i % MM;
        double arg = M_PI * ((double)(y0 + r) / (double)(NN - 1)) * (double)(j + 1);
        sS[i] = (float)sin(arg);
    }
    __syncthreads();

    float au[ROWS_OUT][2] = {}, av[ROWS_OUT][2] = {};
    for (int j = 0; j < MM; ++j) {
        float bu0 = B_u[j * NN + t], bu1 = B_u[j * NN + t + 256];
        float bv0 = B_v[j * NN + t], bv1 = B_v[j * NN + t + 256];
        #pragma unroll
        for (int r = 0; r < ROWS_OUT; ++r) {
            float s = sS[r * MM + j];        // wave-uniform -> broadcast
            au[r][0] += bu0 * s; au[r][1] += bu1 * s;
            av[r][0] += bv0 * s; av[r][1] += bv1 * s;
        }
    }

    float xvq[PXPT], yvq[PXPT];
    int offA[PXPT], offB[PXPT];
    int myf = NN, Myc = -1;
    #pragma unroll
    for (int i = 0; i < PXPT; ++i) {
        int c = i & 1, r = i >> 1;
        int xi = (c << 8) + t;
        int yi = y0 + r;
        float xn = fminf(fmaxf((float)xi - scale * au[r][c], 0.0f), (float)(NN - 1));
        float yn = fminf(fmaxf((float)yi - scale * av[r][c], 0.0f), (float)(NN - 1));
        int xf = (int)floorf(xn), yf = (int)floorf(yn);
        int yc = (int)ceilf(yn);
        xvq[i] = xn - (float)xf;
        yvq[i] = yn - (float)yf;
        offA[i] = (yf << 9) + xf;
        offB[i] = (yc << 9) + xf;
        myf = min(myf, yf);
        Myc = max(Myc, yc);
    }

    for (int d = 32; d; d >>= 1) {
        myf = min(myf, __shfl_xor(myf, d));
        Myc = max(Myc, __shfl_xor(Myc, d));
    }
    int wid = t >> 6;
    if ((t & 63) == 0) { s_mn[wid] = myf; s_mx[wid] = Myc; }
    __syncthreads();
    int r0 = min(min(s_mn[0], s_mn[1]), min(s_mn[2], s_mn[3]));
    int nr = max(max(s_mx[0], s_mx[1]), max(s_mx[2], s_mx[3])) - r0 + 1;
    if (t == 0) { strip_tab[2 * strip] = r0; strip_tab[2 * strip + 1] = nr; }

    int rb = r0 << 9;
    #pragma unroll
    for (int i = 0; i < PXPT; ++i) {
        int pix = ((y0 + (i >> 1)) << 9) + ((i & 1) << 8) + t;
        u32 oa = (u32)(offA[i] - rb);          // fits 16 bits for nr <= 127
        u32 ob = (u32)(offB[i] - rb);
        u32 xq = (u32)__float2int_rn(xvq[i] * 65535.0f);
        u32 yq = (u32)__float2int_rn(yvq[i] * 65535.0f);
        u32x2 v; v[0] = oa | (ob << 16); v[1] = xq | (yq << 16);
        pk[pix] = v;
    }
}

// One plane per block. Lane owns 2 ADJACENT x-px (x=2t,2t+1) x 4 rows:
// pk loads dwordx4 (4/thread), NT stores dwordx2 (4/thread) -> VMEM instrs
// 23 -> 15 per thread with identical line footprint (R11: issue-width theory).
__global__ __launch_bounds__(TPB, 6)
void remap_kernel(const float* __restrict__ img,
                  const u32x2* __restrict__ pk,
                  const int* __restrict__ strip_tab,
                  float* __restrict__ out,
                  int planes) {
    __shared__ __align__(16) float rows[ROWS_LDS * NN + 1];

    // XCD-bijective swizzle (gridDim.x % 8 == 0), plane-major.
    int nb = gridDim.x;
    int bid = blockIdx.x;
    int sid = (bid & 7) * (nb >> 3) + (bid >> 3);
    int plane = sid >> 7;        // 128 strips per plane
    int strip = sid & 127;

    int t = threadIdx.x;
    int r0 = strip_tab[2 * strip];
    int nr = strip_tab[2 * strip + 1];

    const float* __restrict__ ip = img + (size_t)plane * (NN * NN);
    float* __restrict__ op = out + (size_t)plane * (NN * NN);
    int base = ((strip * ROWS_OUT) << 9) + (t << 1);   // x = 2t, 2t+1

    const float qs = 1.0f / 65535.0f;
    const u32x4* __restrict__ pk4 = (const u32x4*)pk;

    if (nr <= ROWS_LDS) {
        // pad slot: read only with weight exactly 0 (xf==511 -> xv=0)
        if (t == 0) rows[nr * NN] = 0.f;

        int nbytes = nr << 11;
        int wave = t >> 6;
        int lane_goff = t * 16;
        const char* ipc = (const char*)(ip + (r0 << 9));
        for (int ob = 0; ob < nbytes; ob += TPB * 16) {
            if (ob + wave * 1024 < nbytes) {
                __builtin_amdgcn_global_load_lds(
                    (const __attribute__((address_space(1))) void*)(ipc + ob + lane_goff),
                    (__attribute__((address_space(3))) void*)((char*)rows + ob + wave * 1024),
                    16, 0, 0);
            }
        }
        __syncthreads();

        #pragma unroll
        for (int r = 0; r < ROWS_OUT; ++r) {
            int pix = base + (r << 9);
            u32x4 p = pk4[pix >> 1];           // pk[pix], pk[pix+1]
            int oA0 = (int)(p[0] & 0xFFFFu), oB0 = (int)(p[0] >> 16);
            float xv0 = (float)(p[1] & 0xFFFFu) * qs;
            float yv0 = (float)(p[1] >> 16) * qs;
            int oA1 = (int)(p[2] & 0xFFFFu), oB1 = (int)(p[2] >> 16);
            float xv1 = (float)(p[3] & 0xFFFFu) * qs;
            float yv1 = (float)(p[3] >> 16) * qs;
            float t0 = (1.f - xv0) * rows[oA0] + xv0 * rows[oA0 + 1];
            float b0 = (1.f - xv0) * rows[oB0] + xv0 * rows[oB0 + 1];
            float t1 = (1.f - xv1) * rows[oA1] + xv1 * rows[oA1 + 1];
            float b1 = (1.f - xv1) * rows[oB1] + xv1 * rows[oB1 + 1];
            f32x2 o;
            o[0] = (1.f - yv0) * t0 + yv0 * b0;
            o[1] = (1.f - yv1) * t1 + yv1 * b1;
            __builtin_nontemporal_store(o, (f32x2*)(op + pix));
        }
    } else {
        // fallback: direct global gathers (never expected; correct anyway)
        int rb = r0 << 9;
        #pragma unroll
        for (int r = 0; r < ROWS_OUT; ++r) {
            int pix = base + (r << 9);
            u32x4 p = pk4[pix >> 1];
            int a0 = (int)(p[0] & 0xFFFFu) + rb, b0i = (int)(p[0] >> 16) + rb;
            float xv0 = (float)(p[1] & 0xFFFFu) * qs;
            float yv0 = (float)(p[1] >> 16) * qs;
            int a1 = (int)(p[2] & 0xFFFFu) + rb, b1i = (int)(p[2] >> 16) + rb;
            float xv1 = (float)(p[3] & 0xFFFFu) * qs;
            float yv1 = (float)(p[3] >> 16) * qs;
            int e0 = ((a0 & 511) == 511) ? 0 : 1;
            int e1 = ((a1 & 511) == 511) ? 0 : 1;
            float t0 = (1.f - xv0) * ip[a0] + xv0 * ip[a0 + e0];
            float bo0 = (1.f - xv0) * ip[b0i] + xv0 * ip[b0i + e0];
            float t1 = (1.f - xv1) * ip[a1] + xv1 * ip[a1 + e1];
            float bo1 = (1.f - xv1) * ip[b1i] + xv1 * ip[b1i + e1];
            f32x2 o;
            o[0] = (1.f - yv0) * t0 + yv0 * bo0;
            o[1] = (1.f - yv1) * t1 + yv1 * bo1;
            __builtin_nontemporal_store(o, (f32x2*)(op + pix));
        }
    }
}

extern "C" void kernel_launch(void* const* d_in, const int* in_sizes, int n_in,
                              void* d_out, int out_size, void* d_ws, size_t ws_size,
                              hipStream_t stream) {
    const float* img = (const float*)d_in[0];
    const float* c_u = (const float*)d_in[1];
    const float* c_v = (const float*)d_in[2];
    float* out = (float*)d_out;

    int planes = in_sizes[0] / (NN * NN);   // 96

    float* ws   = (float*)d_ws;
    float* B_u  = ws;                        // 51200
    float* B_v  = B_u + MM * NN;             // 51200
    u32x2* pk   = (u32x2*)(ws + 2 * MM * NN);            // 2 MB
    int* strip_tab = (int*)(ws + 2 * MM * NN + 2 * NN * NN);

    double log_cut = log((double)MM + 1e-6);
    double T1 = 1.0 / (M_PI * (double)NN * (double)NN * log_cut);
    double T2 = 4.0 / (M_PI * M_PI * M_PI * (double)MM * (double)MM * log_cut);
    if (T2 < T1) T2 = T1;
    double T = 0.5 * (T1 + T2);
    float scale = (float)(sqrt(T) * (double)NN);

    bcoef_kernel<<<NN, 128, 0, stream>>>(c_u, c_v, B_u, B_v);
    field_weights_kernel<<<NN / ROWS_OUT, 256, 0, stream>>>(B_u, B_v, scale,
                                                            pk, strip_tab);

    int strips = NN / ROWS_OUT;                  // 128
    remap_kernel<<<strips * planes, TPB, 0, stream>>>(img, pk, strip_tab,
                                                      out, planes);
}